// Round 1
// baseline (493.520 us; speedup 1.0000x reference)
//
#include <hip/hip_runtime.h>

// SplineCNN on MI355X.
// Structure: sparse edge extraction (adj ~6% dense, basis shared across layers),
// per-layer: packed GEMM [B*N,Cin]x[Cin,9*64+64] -> sparse aggregate (+root+bias+relu),
// then max-pool + FC.

#define B_   32
#define N_   512
#define F_   64
#define CAP  128          // max neighbors stored per node (binomial mean ~31, 128 is >>6 sigma)
#define NCOL 640          // 9*F (spline kernels) + F (root)

// ---------------- preprocess: edge lists + factored spline basis ----------------
__global__ __launch_bounds__(512) void preprocess_kernel(
    const float* __restrict__ adj, const float* __restrict__ coord,
    int* __restrict__ edge_mk, float2* __restrict__ edge_f,
    int* __restrict__ cnt_out, float* __restrict__ deginv_out) {
  int row = blockIdx.x;          // b*N + n
  int b = row >> 9;
  int tid = threadIdx.x;         // == m
  int lane = tid & 63, wave = tid >> 6;
  __shared__ int wcnt[8];
  float a = adj[(size_t)row * N_ + tid];
  bool flag = (a != 0.0f);
  unsigned long long ball = __ballot(flag);
  if (lane == 0) wcnt[wave] = __popcll(ball);
  __syncthreads();
  int woff = 0, total = 0;
  #pragma unroll
  for (int i = 0; i < 8; ++i) { int c = wcnt[i]; if (i < wave) woff += c; total += c; }
  if (flag) {
    int pos = woff + __popcll(ball & ((1ULL << lane) - 1));
    if (pos < CAP) {
      int m = tid;
      float cxn = coord[(size_t)row * 2 + 0];
      float cyn = coord[(size_t)row * 2 + 1];
      float cxm = coord[(size_t)(b * N_ + m) * 2 + 0];
      float cym = coord[(size_t)(b * N_ + m) * 2 + 1];
      // match reference rounding: u = (d+1)*0.5, v = u*2
      float vx = (cxm - cxn + 1.0f) * 0.5f * 2.0f;
      float vy = (cym - cyn + 1.0f) * 0.5f * 2.0f;
      float i0x = fminf(fmaxf(floorf(vx), 0.0f), 1.0f);
      float i0y = fminf(fmaxf(floorf(vy), 0.0f), 1.0f);
      float fx = vx - i0x, fy = vy - i0y;
      int k0c = (int)i0x * 3 + (int)i0y;   // base index into 3x3 kernel grid
      edge_mk[(size_t)row * CAP + pos] = m | (k0c << 16);
      edge_f[(size_t)row * CAP + pos] = make_float2(fx, fy);
    }
  }
  if (tid == 0) {
    cnt_out[row] = total > CAP ? CAP : total;
    deginv_out[row] = 1.0f / (float)(total > 0 ? total : 1);
  }
}

// ---------------- pack w (9 slices) + root into one [Cin, 640] matrix ----------------
__global__ void packw_kernel(const float* __restrict__ w, const float* __restrict__ root,
                             int cin, float* __restrict__ wp) {
  int idx = blockIdx.x * blockDim.x + threadIdx.x;
  int total = cin * NCOL;
  if (idx >= total) return;
  int c = idx / NCOL, j = idx - c * NCOL;
  int kk = j >> 6, f = j & 63;
  float v = (kk < 9) ? w[((size_t)kk * cin + c) * F_ + f]
                     : root[(size_t)c * F_ + f];
  wp[idx] = v;
}

// ---------------- fp32 GEMM: C[M,640] = A[M,K] * W[K,640] ----------------
// 128x128 tile, 256 threads, 8x8 per thread, BK=8
__global__ __launch_bounds__(256) void gemm_kernel(
    const float* __restrict__ A, const float* __restrict__ W,
    float* __restrict__ C, int K) {
  __shared__ float As[8][128];
  __shared__ float Ws[8][128];
  int bm = blockIdx.x * 128;
  int bn = blockIdx.y * 128;
  int tid = threadIdx.x;
  int tx = tid & 15, ty = tid >> 4;
  float acc[8][8] = {{0.0f}};
  for (int k0 = 0; k0 < K; k0 += 8) {
    {
      int r = tid >> 1, cq = (tid & 1) * 4;
      const float4 av = *(const float4*)&A[(size_t)(bm + r) * K + k0 + cq];
      As[cq + 0][r] = av.x; As[cq + 1][r] = av.y;
      As[cq + 2][r] = av.z; As[cq + 3][r] = av.w;
    }
    {
      int r = tid >> 5, cq = (tid & 31) * 4;
      *(float4*)&Ws[r][cq] = *(const float4*)&W[(size_t)(k0 + r) * NCOL + bn + cq];
    }
    __syncthreads();
    #pragma unroll
    for (int kk = 0; kk < 8; ++kk) {
      float a[8], w[8];
      #pragma unroll
      for (int i = 0; i < 8; ++i) a[i] = As[kk][ty * 8 + i];
      #pragma unroll
      for (int j = 0; j < 8; ++j) w[j] = Ws[kk][tx * 8 + j];
      #pragma unroll
      for (int i = 0; i < 8; ++i)
        #pragma unroll
        for (int j = 0; j < 8; ++j)
          acc[i][j] += a[i] * w[j];
    }
    __syncthreads();
  }
  #pragma unroll
  for (int i = 0; i < 8; ++i) {
    size_t off = (size_t)(bm + ty * 8 + i) * NCOL + bn + tx * 8;
    *(float4*)&C[off]     = make_float4(acc[i][0], acc[i][1], acc[i][2], acc[i][3]);
    *(float4*)&C[off + 4] = make_float4(acc[i][4], acc[i][5], acc[i][6], acc[i][7]);
  }
}

// ---------------- sparse aggregate: 4 nonzero basis taps per edge ----------------
__global__ __launch_bounds__(64) void aggregate_kernel(
    const float* __restrict__ hw,
    const int* __restrict__ edge_mk, const float2* __restrict__ edge_f,
    const int* __restrict__ cnt, const float* __restrict__ deginv,
    const float* __restrict__ bias, float* __restrict__ hout) {
  int row = blockIdx.x;            // b*N + n
  int b = row >> 9;
  int f = threadIdx.x;             // 0..63
  int c = cnt[row];
  float di = deginv[row];
  float acc = 0.0f;
  const float* hwb = hw + (size_t)b * N_ * NCOL;
  size_t ebase = (size_t)row * CAP;
  for (int e = 0; e < c; ++e) {
    int mk = edge_mk[ebase + e];
    float2 ff = edge_f[ebase + e];
    int m = mk & 0xffff, k0 = mk >> 16;
    float bx0 = 1.0f - ff.x, bx1 = ff.x;
    float by0 = 1.0f - ff.y, by1 = ff.y;
    const float* p = hwb + (size_t)m * NCOL + k0 * F_ + f;
    acc += (bx0 * by0) * p[0]
         + (bx0 * by1) * p[F_]
         + (bx1 * by0) * p[3 * F_]
         + (bx1 * by1) * p[4 * F_];
  }
  float rootv = hw[(size_t)row * NCOL + 9 * F_ + f];
  float val = acc * di + rootv + bias[f];
  hout[(size_t)row * F_ + f] = fmaxf(val, 0.0f);
}

// ---------------- global max-pool + FC ----------------
__global__ __launch_bounds__(64) void poolfc_kernel(
    const float* __restrict__ h, const float* __restrict__ fcw,
    const float* __restrict__ fcb, float* __restrict__ out) {
  int b = blockIdx.x;
  int f = threadIdx.x;
  __shared__ float gs[64];
  float g = -1e30f;
  const float* hb = h + (size_t)b * N_ * F_;
  for (int n = 0; n < N_; ++n) g = fmaxf(g, hb[n * F_ + f]);
  gs[f] = g;
  __syncthreads();
  if (f < 10) {
    float s = fcb[f];
    #pragma unroll
    for (int c = 0; c < 64; ++c) s += gs[c] * fcw[c * 10 + f];
    out[b * 10 + f] = s;
  }
}

extern "C" void kernel_launch(void* const* d_in, const int* in_sizes, int n_in,
                              void* d_out, int out_size, void* d_ws, size_t ws_size,
                              hipStream_t stream) {
  const float* x     = (const float*)d_in[0];
  const float* coord = (const float*)d_in[1];
  const float* adj   = (const float*)d_in[2];
  const float* w0    = (const float*)d_in[3];
  const float* root0 = (const float*)d_in[4];
  const float* b0    = (const float*)d_in[5];
  const float* w1    = (const float*)d_in[6];
  const float* root1 = (const float*)d_in[7];
  const float* b1    = (const float*)d_in[8];
  const float* w2    = (const float*)d_in[9];
  const float* root2 = (const float*)d_in[10];
  const float* b2    = (const float*)d_in[11];
  const float* fcw   = (const float*)d_in[12];
  const float* fcb   = (const float*)d_in[13];
  float* out = (float*)d_out;

  char* ws = (char*)d_ws;
  size_t off = 0;
  auto alloc = [&](size_t bytes) {
    void* p = ws + off;
    off = (off + bytes + 255) & ~(size_t)255;
    return p;
  };
  const int R = B_ * N_;  // 16384
  int*    edge_mk = (int*)   alloc((size_t)R * CAP * 4);
  float2* edge_f  = (float2*)alloc((size_t)R * CAP * 8);
  int*    cnt     = (int*)   alloc((size_t)R * 4);
  float*  deginv  = (float*) alloc((size_t)R * 4);
  float*  wpack   = (float*) alloc((size_t)128 * NCOL * 4);
  float*  hw      = (float*) alloc((size_t)R * NCOL * 4);
  float*  hb1     = (float*) alloc((size_t)R * F_ * 4);
  float*  hb2     = (float*) alloc((size_t)R * F_ * 4);

  preprocess_kernel<<<R, 512, 0, stream>>>(adj, coord, edge_mk, edge_f, cnt, deginv);

  // layer 0 (Cin=128)
  packw_kernel<<<(128 * NCOL + 255) / 256, 256, 0, stream>>>(w0, root0, 128, wpack);
  gemm_kernel<<<dim3(R / 128, NCOL / 128), 256, 0, stream>>>(x, wpack, hw, 128);
  aggregate_kernel<<<R, 64, 0, stream>>>(hw, edge_mk, edge_f, cnt, deginv, b0, hb1);

  // layer 1 (Cin=64)
  packw_kernel<<<(64 * NCOL + 255) / 256, 256, 0, stream>>>(w1, root1, 64, wpack);
  gemm_kernel<<<dim3(R / 128, NCOL / 128), 256, 0, stream>>>(hb1, wpack, hw, 64);
  aggregate_kernel<<<R, 64, 0, stream>>>(hw, edge_mk, edge_f, cnt, deginv, b1, hb2);

  // layer 2 (Cin=64)
  packw_kernel<<<(64 * NCOL + 255) / 256, 256, 0, stream>>>(w2, root2, 64, wpack);
  gemm_kernel<<<dim3(R / 128, NCOL / 128), 256, 0, stream>>>(hb2, wpack, hw, 64);
  aggregate_kernel<<<R, 64, 0, stream>>>(hw, edge_mk, edge_f, cnt, deginv, b2, hb1);

  poolfc_kernel<<<B_, 64, 0, stream>>>(hb1, fcw, fcb, out);
}

// Round 2
// 398.221 us; speedup vs baseline: 1.2393x; 1.2393x over previous
//
#include <hip/hip_runtime.h>

// SplineCNN on MI355X.
// Structure: sparse edge extraction (adj ~6% dense, basis shared across layers),
// per-layer: packed GEMM [B*N,Cin]x[Cin,9*64+64] -> sparse aggregate (+root+bias+relu),
// layer-2 aggregate fuses global max-pool via uint-bitcast atomicMax (valid: relu >= 0),
// then a tiny FC kernel.

#define B_   32
#define N_   512
#define F_   64
#define CAP  128          // max neighbors stored per node (binomial mean ~31, 128 is >>6 sigma)
#define NCOL 640          // 9*F (spline kernels) + F (root)

// ---------------- preprocess: edge lists + factored spline basis ----------------
__global__ __launch_bounds__(512) void preprocess_kernel(
    const float* __restrict__ adj, const float* __restrict__ coord,
    int* __restrict__ edge_mk, float2* __restrict__ edge_f,
    int* __restrict__ cnt_out, float* __restrict__ deginv_out) {
  int row = blockIdx.x;          // b*N + n
  int b = row >> 9;
  int tid = threadIdx.x;         // == m
  int lane = tid & 63, wave = tid >> 6;
  __shared__ int wcnt[8];
  float a = adj[(size_t)row * N_ + tid];
  bool flag = (a != 0.0f);
  unsigned long long ball = __ballot(flag);
  if (lane == 0) wcnt[wave] = __popcll(ball);
  __syncthreads();
  int woff = 0, total = 0;
  #pragma unroll
  for (int i = 0; i < 8; ++i) { int c = wcnt[i]; if (i < wave) woff += c; total += c; }
  if (flag) {
    int pos = woff + __popcll(ball & ((1ULL << lane) - 1));
    if (pos < CAP) {
      int m = tid;
      float cxn = coord[(size_t)row * 2 + 0];
      float cyn = coord[(size_t)row * 2 + 1];
      float cxm = coord[(size_t)(b * N_ + m) * 2 + 0];
      float cym = coord[(size_t)(b * N_ + m) * 2 + 1];
      // match reference rounding: u = (d+1)*0.5, v = u*2
      float vx = (cxm - cxn + 1.0f) * 0.5f * 2.0f;
      float vy = (cym - cyn + 1.0f) * 0.5f * 2.0f;
      float i0x = fminf(fmaxf(floorf(vx), 0.0f), 1.0f);
      float i0y = fminf(fmaxf(floorf(vy), 0.0f), 1.0f);
      float fx = vx - i0x, fy = vy - i0y;
      int k0c = (int)i0x * 3 + (int)i0y;   // base index into 3x3 kernel grid
      edge_mk[(size_t)row * CAP + pos] = m | (k0c << 16);
      edge_f[(size_t)row * CAP + pos] = make_float2(fx, fy);
    }
  }
  if (tid == 0) {
    cnt_out[row] = total > CAP ? CAP : total;
    deginv_out[row] = 1.0f / (float)(total > 0 ? total : 1);
  }
}

// ---------------- pack w (9 slices) + root into one [Cin, 640] matrix ----------------
__global__ void packw_kernel(const float* __restrict__ w, const float* __restrict__ root,
                             int cin, float* __restrict__ wp) {
  int idx = blockIdx.x * blockDim.x + threadIdx.x;
  int total = cin * NCOL;
  if (idx >= total) return;
  int c = idx / NCOL, j = idx - c * NCOL;
  int kk = j >> 6, f = j & 63;
  float v = (kk < 9) ? w[((size_t)kk * cin + c) * F_ + f]
                     : root[(size_t)c * F_ + f];
  wp[idx] = v;
}

// ---------------- fp32 GEMM: C[M,640] = A[M,K] * W[K,640] ----------------
// 128x128 tile, 256 threads, 8x8 per thread, BK=8
__global__ __launch_bounds__(256) void gemm_kernel(
    const float* __restrict__ A, const float* __restrict__ W,
    float* __restrict__ C, int K) {
  __shared__ float As[8][128];
  __shared__ float Ws[8][128];
  int bm = blockIdx.x * 128;
  int bn = blockIdx.y * 128;
  int tid = threadIdx.x;
  int tx = tid & 15, ty = tid >> 4;
  float acc[8][8] = {{0.0f}};
  for (int k0 = 0; k0 < K; k0 += 8) {
    {
      int r = tid >> 1, cq = (tid & 1) * 4;
      const float4 av = *(const float4*)&A[(size_t)(bm + r) * K + k0 + cq];
      As[cq + 0][r] = av.x; As[cq + 1][r] = av.y;
      As[cq + 2][r] = av.z; As[cq + 3][r] = av.w;
    }
    {
      int r = tid >> 5, cq = (tid & 31) * 4;
      *(float4*)&Ws[r][cq] = *(const float4*)&W[(size_t)(k0 + r) * NCOL + bn + cq];
    }
    __syncthreads();
    #pragma unroll
    for (int kk = 0; kk < 8; ++kk) {
      float a[8], w[8];
      #pragma unroll
      for (int i = 0; i < 8; ++i) a[i] = As[kk][ty * 8 + i];
      #pragma unroll
      for (int j = 0; j < 8; ++j) w[j] = Ws[kk][tx * 8 + j];
      #pragma unroll
      for (int i = 0; i < 8; ++i)
        #pragma unroll
        for (int j = 0; j < 8; ++j)
          acc[i][j] += a[i] * w[j];
    }
    __syncthreads();
  }
  #pragma unroll
  for (int i = 0; i < 8; ++i) {
    size_t off = (size_t)(bm + ty * 8 + i) * NCOL + bn + tx * 8;
    *(float4*)&C[off]     = make_float4(acc[i][0], acc[i][1], acc[i][2], acc[i][3]);
    *(float4*)&C[off + 4] = make_float4(acc[i][4], acc[i][5], acc[i][6], acc[i][7]);
  }
}

// ---------------- sparse aggregate: 4 nonzero basis taps per edge ----------------
// 256 threads = 4 waves, one row per wave. Optional fused max-pool (gmax != null).
__global__ __launch_bounds__(256) void aggregate_kernel(
    const float* __restrict__ hw,
    const int* __restrict__ edge_mk, const float2* __restrict__ edge_f,
    const int* __restrict__ cnt, const float* __restrict__ deginv,
    const float* __restrict__ bias, float* __restrict__ hout,
    unsigned int* __restrict__ gmax) {
  int wave = threadIdx.x >> 6;
  int f = threadIdx.x & 63;
  int row = blockIdx.x * 4 + wave;   // b*N + n
  int b = row >> 9;
  int c = cnt[row];
  float di = deginv[row];
  float acc = 0.0f;
  const float* hwb = hw + (size_t)b * N_ * NCOL;
  size_t ebase = (size_t)row * CAP;
  for (int e = 0; e < c; ++e) {
    int mk = edge_mk[ebase + e];
    float2 ff = edge_f[ebase + e];
    int m = mk & 0xffff, k0 = mk >> 16;
    float bx0 = 1.0f - ff.x, bx1 = ff.x;
    float by0 = 1.0f - ff.y, by1 = ff.y;
    const float* p = hwb + (size_t)m * NCOL + k0 * F_ + f;
    acc += (bx0 * by0) * p[0]
         + (bx0 * by1) * p[F_]
         + (bx1 * by0) * p[3 * F_]
         + (bx1 * by1) * p[4 * F_];
  }
  float rootv = hw[(size_t)row * NCOL + 9 * F_ + f];
  float val = fmaxf(acc * di + rootv + bias[f], 0.0f);
  hout[(size_t)row * F_ + f] = val;
  if (gmax) {
    // relu output >= 0 -> IEEE bits monotone under unsigned compare
    atomicMax(&gmax[b * F_ + f], __float_as_uint(val));
  }
}

// ---------------- zero the pooled-max buffer ----------------
__global__ void zerog_kernel(unsigned int* __restrict__ g) {
  int i = blockIdx.x * blockDim.x + threadIdx.x;
  if (i < B_ * F_) g[i] = 0u;
}

// ---------------- FC from pooled features ----------------
__global__ __launch_bounds__(64) void fc_kernel(
    const float* __restrict__ g, const float* __restrict__ fcw,
    const float* __restrict__ fcb, float* __restrict__ out) {
  int b = blockIdx.x;
  int f = threadIdx.x;
  __shared__ float gs[64];
  gs[f] = g[b * F_ + f];
  __syncthreads();
  if (f < 10) {
    float s = fcb[f];
    #pragma unroll
    for (int c = 0; c < 64; ++c) s += gs[c] * fcw[c * 10 + f];
    out[b * 10 + f] = s;
  }
}

extern "C" void kernel_launch(void* const* d_in, const int* in_sizes, int n_in,
                              void* d_out, int out_size, void* d_ws, size_t ws_size,
                              hipStream_t stream) {
  const float* x     = (const float*)d_in[0];
  const float* coord = (const float*)d_in[1];
  const float* adj   = (const float*)d_in[2];
  const float* w0    = (const float*)d_in[3];
  const float* root0 = (const float*)d_in[4];
  const float* b0    = (const float*)d_in[5];
  const float* w1    = (const float*)d_in[6];
  const float* root1 = (const float*)d_in[7];
  const float* b1    = (const float*)d_in[8];
  const float* w2    = (const float*)d_in[9];
  const float* root2 = (const float*)d_in[10];
  const float* b2    = (const float*)d_in[11];
  const float* fcw   = (const float*)d_in[12];
  const float* fcb   = (const float*)d_in[13];
  float* out = (float*)d_out;

  char* ws = (char*)d_ws;
  size_t off = 0;
  auto alloc = [&](size_t bytes) {
    void* p = ws + off;
    off = (off + bytes + 255) & ~(size_t)255;
    return p;
  };
  const int R = B_ * N_;  // 16384
  int*    edge_mk = (int*)   alloc((size_t)R * CAP * 4);
  float2* edge_f  = (float2*)alloc((size_t)R * CAP * 8);
  int*    cnt     = (int*)   alloc((size_t)R * 4);
  float*  deginv  = (float*) alloc((size_t)R * 4);
  float*  wpack   = (float*) alloc((size_t)128 * NCOL * 4);
  float*  hw      = (float*) alloc((size_t)R * NCOL * 4);
  float*  hb1     = (float*) alloc((size_t)R * F_ * 4);
  float*  hb2     = (float*) alloc((size_t)R * F_ * 4);
  unsigned int* gmax = (unsigned int*)alloc((size_t)B_ * F_ * 4);

  preprocess_kernel<<<R, 512, 0, stream>>>(adj, coord, edge_mk, edge_f, cnt, deginv);
  zerog_kernel<<<(B_ * F_ + 255) / 256, 256, 0, stream>>>(gmax);

  // layer 0 (Cin=128)
  packw_kernel<<<(128 * NCOL + 255) / 256, 256, 0, stream>>>(w0, root0, 128, wpack);
  gemm_kernel<<<dim3(R / 128, NCOL / 128), 256, 0, stream>>>(x, wpack, hw, 128);
  aggregate_kernel<<<R / 4, 256, 0, stream>>>(hw, edge_mk, edge_f, cnt, deginv, b0, hb1, nullptr);

  // layer 1 (Cin=64)
  packw_kernel<<<(64 * NCOL + 255) / 256, 256, 0, stream>>>(w1, root1, 64, wpack);
  gemm_kernel<<<dim3(R / 128, NCOL / 128), 256, 0, stream>>>(hb1, wpack, hw, 64);
  aggregate_kernel<<<R / 4, 256, 0, stream>>>(hw, edge_mk, edge_f, cnt, deginv, b1, hb2, nullptr);

  // layer 2 (Cin=64) — fused max-pool
  packw_kernel<<<(64 * NCOL + 255) / 256, 256, 0, stream>>>(w2, root2, 64, wpack);
  gemm_kernel<<<dim3(R / 128, NCOL / 128), 256, 0, stream>>>(hb2, wpack, hw, 64);
  aggregate_kernel<<<R / 4, 256, 0, stream>>>(hw, edge_mk, edge_f, cnt, deginv, b2, hb1, gmax);

  fc_kernel<<<B_, 64, 0, stream>>>((const float*)gmax, fcw, fcb, out);
}

// Round 3
// 349.473 us; speedup vs baseline: 1.4122x; 1.1395x over previous
//
#include <hip/hip_runtime.h>

// SplineCNN on MI355X.
// Sparse edge extraction (adj ~6% dense, basis shared across layers);
// per-layer: packed GEMM [B*N,Cin]x[Cin,9*64+64] -> sparse aggregate (+root+bias+relu).
// Aggregate grid is XCD-swizzled so each XCD's L2 holds only its 4 batches' hw slices.
// Layer-2 aggregate fuses global max-pool via uint-bitcast atomicMax (valid: relu >= 0).

#define B_   32
#define N_   512
#define F_   64
#define CAP  128          // max neighbors per node (mean ~31, 128 is >>6 sigma)
#define NCOL 640          // 9*F (spline kernels) + F (root)

// ---------------- preprocess: edge lists + factored spline basis ----------------
// edge record: float4 { bitcast(m | k0<<16), fx, fy, 0 }
__global__ __launch_bounds__(512) void preprocess_kernel(
    const float* __restrict__ adj, const float* __restrict__ coord,
    float4* __restrict__ edge, int* __restrict__ cnt_out,
    float* __restrict__ deginv_out) {
  int row = blockIdx.x;          // b*N + n
  int b = row >> 9;
  int tid = threadIdx.x;         // == m
  int lane = tid & 63, wave = tid >> 6;
  __shared__ int wcnt[8];
  float a = adj[(size_t)row * N_ + tid];
  bool flag = (a != 0.0f);
  unsigned long long ball = __ballot(flag);
  if (lane == 0) wcnt[wave] = __popcll(ball);
  __syncthreads();
  int woff = 0, total = 0;
  #pragma unroll
  for (int i = 0; i < 8; ++i) { int c = wcnt[i]; if (i < wave) woff += c; total += c; }
  if (flag) {
    int pos = woff + __popcll(ball & ((1ULL << lane) - 1));
    if (pos < CAP) {
      int m = tid;
      float cxn = coord[(size_t)row * 2 + 0];
      float cyn = coord[(size_t)row * 2 + 1];
      float cxm = coord[(size_t)(b * N_ + m) * 2 + 0];
      float cym = coord[(size_t)(b * N_ + m) * 2 + 1];
      // match reference rounding: u = (d+1)*0.5, v = u*(K-1)=u*2
      float vx = (cxm - cxn + 1.0f) * 0.5f * 2.0f;
      float vy = (cym - cyn + 1.0f) * 0.5f * 2.0f;
      float i0x = fminf(fmaxf(floorf(vx), 0.0f), 1.0f);
      float i0y = fminf(fmaxf(floorf(vy), 0.0f), 1.0f);
      float fx = vx - i0x, fy = vy - i0y;
      int k0c = (int)i0x * 3 + (int)i0y;   // base index into 3x3 kernel grid
      edge[(size_t)row * CAP + pos] =
          make_float4(__int_as_float(m | (k0c << 16)), fx, fy, 0.0f);
    }
  }
  if (tid == 0) {
    cnt_out[row] = total > CAP ? CAP : total;
    deginv_out[row] = 1.0f / (float)(total > 0 ? total : 1);
  }
}

// ---------------- pack w (9 slices) + root into one [Cin, 640] matrix ----------------
__global__ void packw_kernel(const float* __restrict__ w, const float* __restrict__ root,
                             int cin, float* __restrict__ wp) {
  int idx = blockIdx.x * blockDim.x + threadIdx.x;
  int total = cin * NCOL;
  if (idx >= total) return;
  int c = idx / NCOL, j = idx - c * NCOL;
  int kk = j >> 6, f = j & 63;
  float v = (kk < 9) ? w[((size_t)kk * cin + c) * F_ + f]
                     : root[(size_t)c * F_ + f];
  wp[idx] = v;
}

// ---------------- fp32 GEMM: C[M,640] = A[M,K] * W[K,640] ----------------
// 128x128 tile, 256 threads, 8x8 per thread, BK=8
__global__ __launch_bounds__(256) void gemm_kernel(
    const float* __restrict__ A, const float* __restrict__ W,
    float* __restrict__ C, int K) {
  __shared__ float As[8][128];
  __shared__ float Ws[8][128];
  int bm = blockIdx.x * 128;
  int bn = blockIdx.y * 128;
  int tid = threadIdx.x;
  int tx = tid & 15, ty = tid >> 4;
  float acc[8][8] = {{0.0f}};
  for (int k0 = 0; k0 < K; k0 += 8) {
    {
      int r = tid >> 1, cq = (tid & 1) * 4;
      const float4 av = *(const float4*)&A[(size_t)(bm + r) * K + k0 + cq];
      As[cq + 0][r] = av.x; As[cq + 1][r] = av.y;
      As[cq + 2][r] = av.z; As[cq + 3][r] = av.w;
    }
    {
      int r = tid >> 5, cq = (tid & 31) * 4;
      *(float4*)&Ws[r][cq] = *(const float4*)&W[(size_t)(k0 + r) * NCOL + bn + cq];
    }
    __syncthreads();
    #pragma unroll
    for (int kk = 0; kk < 8; ++kk) {
      float a[8], w[8];
      *(float4*)&a[0] = *(const float4*)&As[kk][ty * 8];
      *(float4*)&a[4] = *(const float4*)&As[kk][ty * 8 + 4];
      *(float4*)&w[0] = *(const float4*)&Ws[kk][tx * 8];
      *(float4*)&w[4] = *(const float4*)&Ws[kk][tx * 8 + 4];
      #pragma unroll
      for (int i = 0; i < 8; ++i)
        #pragma unroll
        for (int j = 0; j < 8; ++j)
          acc[i][j] += a[i] * w[j];
    }
    __syncthreads();
  }
  #pragma unroll
  for (int i = 0; i < 8; ++i) {
    size_t off = (size_t)(bm + ty * 8 + i) * NCOL + bn + tx * 8;
    *(float4*)&C[off]     = make_float4(acc[i][0], acc[i][1], acc[i][2], acc[i][3]);
    *(float4*)&C[off + 4] = make_float4(acc[i][4], acc[i][5], acc[i][6], acc[i][7]);
  }
}

// ---------------- sparse aggregate: 4 nonzero basis taps per edge ----------------
// 256 threads = 4 waves, one row per wave. XCD-swizzled: blockIdx&7 selects the XCD,
// each XCD owns 4 consecutive batches -> hw[b] slices stay L2-resident (4x1.31MB < 4MB).
__global__ __launch_bounds__(256) void aggregate_kernel(
    const float* __restrict__ hw,
    const float4* __restrict__ edge,
    const int* __restrict__ cnt, const float* __restrict__ deginv,
    const float* __restrict__ bias, float* __restrict__ hout,
    unsigned int* __restrict__ gmax) {
  int wave = threadIdx.x >> 6;
  int f = threadIdx.x & 63;
  // swizzle: xcd j in [0,512): b = xcd*4 + j/128, rowInB = (j%128)*4 + wave
  int xcd = blockIdx.x & 7;
  int j = blockIdx.x >> 3;
  int b = xcd * 4 + (j >> 7);
  int row = b * N_ + ((j & 127) << 2) + wave;
  int c = cnt[row];
  float di = deginv[row];
  float acc0 = 0.0f, acc1 = 0.0f;
  const float* hwb = hw + (size_t)b * N_ * NCOL;
  size_t ebase = (size_t)row * CAP;
  int e = 0;
  for (; e + 1 < c; e += 2) {
    float4 er0 = edge[ebase + e];
    float4 er1 = edge[ebase + e + 1];
    int mk0 = __float_as_int(er0.x);
    int mk1 = __float_as_int(er1.x);
    const float* p0 = hwb + (size_t)(mk0 & 0xffff) * NCOL + (mk0 >> 16) * F_ + f;
    const float* p1 = hwb + (size_t)(mk1 & 0xffff) * NCOL + (mk1 >> 16) * F_ + f;
    float bx0 = 1.0f - er0.y, by0 = 1.0f - er0.z;
    float cx0 = 1.0f - er1.y, cy0 = 1.0f - er1.z;
    acc0 += (bx0 * by0) * p0[0]
          + (bx0 * er0.z) * p0[F_]
          + (er0.y * by0) * p0[3 * F_]
          + (er0.y * er0.z) * p0[4 * F_];
    acc1 += (cx0 * cy0) * p1[0]
          + (cx0 * er1.z) * p1[F_]
          + (er1.y * cy0) * p1[3 * F_]
          + (er1.y * er1.z) * p1[4 * F_];
  }
  if (e < c) {
    float4 er0 = edge[ebase + e];
    int mk0 = __float_as_int(er0.x);
    const float* p0 = hwb + (size_t)(mk0 & 0xffff) * NCOL + (mk0 >> 16) * F_ + f;
    float bx0 = 1.0f - er0.y, by0 = 1.0f - er0.z;
    acc0 += (bx0 * by0) * p0[0]
          + (bx0 * er0.z) * p0[F_]
          + (er0.y * by0) * p0[3 * F_]
          + (er0.y * er0.z) * p0[4 * F_];
  }
  float rootv = hw[(size_t)row * NCOL + 9 * F_ + f];
  float val = fmaxf((acc0 + acc1) * di + rootv + bias[f], 0.0f);
  hout[(size_t)row * F_ + f] = val;
  if (gmax) {
    // relu output >= 0 -> IEEE bits monotone under unsigned compare
    atomicMax(&gmax[b * F_ + f], __float_as_uint(val));
  }
}

// ---------------- zero the pooled-max buffer ----------------
__global__ void zerog_kernel(unsigned int* __restrict__ g) {
  int i = blockIdx.x * blockDim.x + threadIdx.x;
  if (i < B_ * F_) g[i] = 0u;
}

// ---------------- FC from pooled features ----------------
__global__ __launch_bounds__(64) void fc_kernel(
    const float* __restrict__ g, const float* __restrict__ fcw,
    const float* __restrict__ fcb, float* __restrict__ out) {
  int b = blockIdx.x;
  int f = threadIdx.x;
  __shared__ float gs[64];
  gs[f] = g[b * F_ + f];
  __syncthreads();
  if (f < 10) {
    float s = fcb[f];
    #pragma unroll
    for (int c = 0; c < 64; ++c) s += gs[c] * fcw[c * 10 + f];
    out[b * 10 + f] = s;
  }
}

extern "C" void kernel_launch(void* const* d_in, const int* in_sizes, int n_in,
                              void* d_out, int out_size, void* d_ws, size_t ws_size,
                              hipStream_t stream) {
  const float* x     = (const float*)d_in[0];
  const float* coord = (const float*)d_in[1];
  const float* adj   = (const float*)d_in[2];
  const float* w0    = (const float*)d_in[3];
  const float* root0 = (const float*)d_in[4];
  const float* b0    = (const float*)d_in[5];
  const float* w1    = (const float*)d_in[6];
  const float* root1 = (const float*)d_in[7];
  const float* b1    = (const float*)d_in[8];
  const float* w2    = (const float*)d_in[9];
  const float* root2 = (const float*)d_in[10];
  const float* b2    = (const float*)d_in[11];
  const float* fcw   = (const float*)d_in[12];
  const float* fcb   = (const float*)d_in[13];
  float* out = (float*)d_out;

  char* ws = (char*)d_ws;
  size_t off = 0;
  auto alloc = [&](size_t bytes) {
    void* p = ws + off;
    off = (off + bytes + 255) & ~(size_t)255;
    return p;
  };
  const int R = B_ * N_;  // 16384
  float4* edge    = (float4*)alloc((size_t)R * CAP * 16);
  int*    cnt     = (int*)   alloc((size_t)R * 4);
  float*  deginv  = (float*) alloc((size_t)R * 4);
  float*  wpack   = (float*) alloc((size_t)128 * NCOL * 4);
  float*  hw      = (float*) alloc((size_t)R * NCOL * 4);
  float*  hb1     = (float*) alloc((size_t)R * F_ * 4);
  float*  hb2     = (float*) alloc((size_t)R * F_ * 4);
  unsigned int* gmax = (unsigned int*)alloc((size_t)B_ * F_ * 4);

  preprocess_kernel<<<R, 512, 0, stream>>>(adj, coord, edge, cnt, deginv);
  zerog_kernel<<<(B_ * F_ + 255) / 256, 256, 0, stream>>>(gmax);

  // layer 0 (Cin=128)
  packw_kernel<<<(128 * NCOL + 255) / 256, 256, 0, stream>>>(w0, root0, 128, wpack);
  gemm_kernel<<<dim3(R / 128, NCOL / 128), 256, 0, stream>>>(x, wpack, hw, 128);
  aggregate_kernel<<<R / 4, 256, 0, stream>>>(hw, edge, cnt, deginv, b0, hb1, nullptr);

  // layer 1 (Cin=64)
  packw_kernel<<<(64 * NCOL + 255) / 256, 256, 0, stream>>>(w1, root1, 64, wpack);
  gemm_kernel<<<dim3(R / 128, NCOL / 128), 256, 0, stream>>>(hb1, wpack, hw, 64);
  aggregate_kernel<<<R / 4, 256, 0, stream>>>(hw, edge, cnt, deginv, b1, hb2, nullptr);

  // layer 2 (Cin=64) — fused max-pool
  packw_kernel<<<(64 * NCOL + 255) / 256, 256, 0, stream>>>(w2, root2, 64, wpack);
  gemm_kernel<<<dim3(R / 128, NCOL / 128), 256, 0, stream>>>(hb2, wpack, hw, 64);
  aggregate_kernel<<<R / 4, 256, 0, stream>>>(hw, edge, cnt, deginv, b2, hb1, gmax);

  fc_kernel<<<B_, 64, 0, stream>>>((const float*)gmax, fcw, fcb, out);
}

// Round 4
// 315.865 us; speedup vs baseline: 1.5624x; 1.1064x over previous
//
#include <hip/hip_runtime.h>

// SplineCNN on MI355X.
// Sparse edge extraction (adj ~6% dense, basis shared across layers);
// per-layer: packed GEMM [B*N,Cin]x[Cin,9*64+64] -> sparse aggregate (+root+bias+relu).
// Aggregate: XCD-swizzled grid (L2 locality), LDS-staged edge lists, x4-unrolled
// gather loop with 4 accumulators for L2-latency hiding.
// Layer-2 aggregate fuses global max-pool via uint-bitcast atomicMax (valid: relu >= 0).

#define B_   32
#define N_   512
#define F_   64
#define CAP  128          // max neighbors per node (mean ~31, 128 is >>6 sigma)
#define NCOL 640          // 9*F (spline kernels) + F (root)

// ---------------- preprocess: edge lists + factored spline basis ----------------
// edge record: float4 { bitcast(m | k0<<16), fx, fy, 1.0 }  (w=1.0 marks valid;
// zero-filled records give all-zero tap weights (w-fx)(w-fy) etc.)
__global__ __launch_bounds__(512) void preprocess_kernel(
    const float* __restrict__ adj, const float* __restrict__ coord,
    float4* __restrict__ edge, int* __restrict__ cnt_out,
    float* __restrict__ deginv_out) {
  int row = blockIdx.x;          // b*N + n
  int b = row >> 9;
  int tid = threadIdx.x;         // == m
  int lane = tid & 63, wave = tid >> 6;
  __shared__ int wcnt[8];
  float a = adj[(size_t)row * N_ + tid];
  bool flag = (a != 0.0f);
  unsigned long long ball = __ballot(flag);
  if (lane == 0) wcnt[wave] = __popcll(ball);
  __syncthreads();
  int woff = 0, total = 0;
  #pragma unroll
  for (int i = 0; i < 8; ++i) { int c = wcnt[i]; if (i < wave) woff += c; total += c; }
  if (flag) {
    int pos = woff + __popcll(ball & ((1ULL << lane) - 1));
    if (pos < CAP) {
      int m = tid;
      float cxn = coord[(size_t)row * 2 + 0];
      float cyn = coord[(size_t)row * 2 + 1];
      float cxm = coord[(size_t)(b * N_ + m) * 2 + 0];
      float cym = coord[(size_t)(b * N_ + m) * 2 + 1];
      // match reference rounding: u = (d+1)*0.5, v = u*(K-1)=u*2
      float vx = (cxm - cxn + 1.0f) * 0.5f * 2.0f;
      float vy = (cym - cyn + 1.0f) * 0.5f * 2.0f;
      float i0x = fminf(fmaxf(floorf(vx), 0.0f), 1.0f);
      float i0y = fminf(fmaxf(floorf(vy), 0.0f), 1.0f);
      float fx = vx - i0x, fy = vy - i0y;
      int k0c = (int)i0x * 3 + (int)i0y;   // base index into 3x3 kernel grid
      edge[(size_t)row * CAP + pos] =
          make_float4(__int_as_float(m | (k0c << 16)), fx, fy, 1.0f);
    }
  }
  if (tid == 0) {
    cnt_out[row] = total > CAP ? CAP : total;
    deginv_out[row] = 1.0f / (float)(total > 0 ? total : 1);
  }
}

// ---------------- pack w (9 slices) + root into one [Cin, 640] matrix ----------------
__global__ void packw_kernel(const float* __restrict__ w, const float* __restrict__ root,
                             int cin, float* __restrict__ wp) {
  int idx = blockIdx.x * blockDim.x + threadIdx.x;
  int total = cin * NCOL;
  if (idx >= total) return;
  int c = idx / NCOL, j = idx - c * NCOL;
  int kk = j >> 6, f = j & 63;
  float v = (kk < 9) ? w[((size_t)kk * cin + c) * F_ + f]
                     : root[(size_t)c * F_ + f];
  wp[idx] = v;
}

// ---------------- fp32 GEMM: C[M,640] = A[M,K] * W[K,640] ----------------
// 128x128 tile, 256 threads, 8x8 per thread, BK=8
__global__ __launch_bounds__(256) void gemm_kernel(
    const float* __restrict__ A, const float* __restrict__ W,
    float* __restrict__ C, int K) {
  __shared__ float As[8][128];
  __shared__ float Ws[8][128];
  int bm = blockIdx.x * 128;
  int bn = blockIdx.y * 128;
  int tid = threadIdx.x;
  int tx = tid & 15, ty = tid >> 4;
  float acc[8][8] = {{0.0f}};
  for (int k0 = 0; k0 < K; k0 += 8) {
    {
      int r = tid >> 1, cq = (tid & 1) * 4;
      const float4 av = *(const float4*)&A[(size_t)(bm + r) * K + k0 + cq];
      As[cq + 0][r] = av.x; As[cq + 1][r] = av.y;
      As[cq + 2][r] = av.z; As[cq + 3][r] = av.w;
    }
    {
      int r = tid >> 5, cq = (tid & 31) * 4;
      *(float4*)&Ws[r][cq] = *(const float4*)&W[(size_t)(k0 + r) * NCOL + bn + cq];
    }
    __syncthreads();
    #pragma unroll
    for (int kk = 0; kk < 8; ++kk) {
      float a[8], w[8];
      *(float4*)&a[0] = *(const float4*)&As[kk][ty * 8];
      *(float4*)&a[4] = *(const float4*)&As[kk][ty * 8 + 4];
      *(float4*)&w[0] = *(const float4*)&Ws[kk][tx * 8];
      *(float4*)&w[4] = *(const float4*)&Ws[kk][tx * 8 + 4];
      #pragma unroll
      for (int i = 0; i < 8; ++i)
        #pragma unroll
        for (int j = 0; j < 8; ++j)
          acc[i][j] += a[i] * w[j];
    }
    __syncthreads();
  }
  #pragma unroll
  for (int i = 0; i < 8; ++i) {
    size_t off = (size_t)(bm + ty * 8 + i) * NCOL + bn + tx * 8;
    *(float4*)&C[off]     = make_float4(acc[i][0], acc[i][1], acc[i][2], acc[i][3]);
    *(float4*)&C[off + 4] = make_float4(acc[i][4], acc[i][5], acc[i][6], acc[i][7]);
  }
}

// ---------------- sparse aggregate ----------------
// 256 threads = 4 waves, one row per wave. XCD-swizzled (blockIdx&7 = XCD).
// Edge lists staged to LDS (coalesced float4), padded to x4 with zero records.
// x4 unrolled gather: 16 independent global loads in flight per wave.
__global__ __launch_bounds__(256) void aggregate_kernel(
    const float* __restrict__ hw,
    const float4* __restrict__ edge,
    const int* __restrict__ cnt, const float* __restrict__ deginv,
    const float* __restrict__ bias, float* __restrict__ hout,
    unsigned int* __restrict__ gmax) {
  __shared__ float4 esh[4][CAP];
  int wave = threadIdx.x >> 6;
  int lane = threadIdx.x & 63;
  int f = lane;
  // swizzle: b = xcd*4 + j/128, rowInB = (j%128)*4 + wave
  int xcd = blockIdx.x & 7;
  int j = blockIdx.x >> 3;
  int b = xcd * 4 + (j >> 7);
  int row = b * N_ + ((j & 127) << 2) + wave;
  int c = cnt[row];
  int cpad = (c + 3) & ~3;
  size_t ebase = (size_t)row * CAP;
  for (int i = lane; i < cpad; i += 64)
    esh[wave][i] = (i < c) ? edge[ebase + i] : make_float4(0.f, 0.f, 0.f, 0.f);
  __syncthreads();

  float di = deginv[row];
  const float* hwb = hw + (size_t)b * N_ * NCOL;
  float acc0 = 0.f, acc1 = 0.f, acc2 = 0.f, acc3 = 0.f;
  for (int e0 = 0; e0 < cpad; e0 += 4) {
    int off[4];
    float w00[4], w01[4], w10[4], w11[4];
    #pragma unroll
    for (int q = 0; q < 4; ++q) {
      float4 er = esh[wave][e0 + q];
      int mk = __float_as_int(er.x);
      off[q] = (mk & 0xffff) * NCOL + (mk >> 16) * F_ + f;
      float bx1 = er.y, by1 = er.z, v = er.w;
      float bx0 = v - bx1, by0 = v - by1;
      w00[q] = bx0 * by0; w01[q] = bx0 * by1;
      w10[q] = bx1 * by0; w11[q] = bx1 * by1;
    }
    float t0[4], t1[4], t2[4], t3[4];
    #pragma unroll
    for (int q = 0; q < 4; ++q) {
      const float* p = hwb + off[q];
      t0[q] = p[0]; t1[q] = p[F_]; t2[q] = p[3 * F_]; t3[q] = p[4 * F_];
    }
    acc0 += w00[0] * t0[0] + w01[0] * t1[0] + w10[0] * t2[0] + w11[0] * t3[0];
    acc1 += w00[1] * t0[1] + w01[1] * t1[1] + w10[1] * t2[1] + w11[1] * t3[1];
    acc2 += w00[2] * t0[2] + w01[2] * t1[2] + w10[2] * t2[2] + w11[2] * t3[2];
    acc3 += w00[3] * t0[3] + w01[3] * t1[3] + w10[3] * t2[3] + w11[3] * t3[3];
  }
  float rootv = hw[(size_t)row * NCOL + 9 * F_ + f];
  float val = fmaxf(((acc0 + acc1) + (acc2 + acc3)) * di + rootv + bias[f], 0.0f);
  hout[(size_t)row * F_ + f] = val;
  if (gmax) {
    // relu output >= 0 -> IEEE bits monotone under unsigned compare
    atomicMax(&gmax[b * F_ + f], __float_as_uint(val));
  }
}

// ---------------- zero the pooled-max buffer ----------------
__global__ void zerog_kernel(unsigned int* __restrict__ g) {
  int i = blockIdx.x * blockDim.x + threadIdx.x;
  if (i < B_ * F_) g[i] = 0u;
}

// ---------------- FC from pooled features ----------------
__global__ __launch_bounds__(64) void fc_kernel(
    const float* __restrict__ g, const float* __restrict__ fcw,
    const float* __restrict__ fcb, float* __restrict__ out) {
  int b = blockIdx.x;
  int f = threadIdx.x;
  __shared__ float gs[64];
  gs[f] = g[b * F_ + f];
  __syncthreads();
  if (f < 10) {
    float s = fcb[f];
    #pragma unroll
    for (int c = 0; c < 64; ++c) s += gs[c] * fcw[c * 10 + f];
    out[b * 10 + f] = s;
  }
}

extern "C" void kernel_launch(void* const* d_in, const int* in_sizes, int n_in,
                              void* d_out, int out_size, void* d_ws, size_t ws_size,
                              hipStream_t stream) {
  const float* x     = (const float*)d_in[0];
  const float* coord = (const float*)d_in[1];
  const float* adj   = (const float*)d_in[2];
  const float* w0    = (const float*)d_in[3];
  const float* root0 = (const float*)d_in[4];
  const float* b0    = (const float*)d_in[5];
  const float* w1    = (const float*)d_in[6];
  const float* root1 = (const float*)d_in[7];
  const float* b1    = (const float*)d_in[8];
  const float* w2    = (const float*)d_in[9];
  const float* root2 = (const float*)d_in[10];
  const float* b2    = (const float*)d_in[11];
  const float* fcw   = (const float*)d_in[12];
  const float* fcb   = (const float*)d_in[13];
  float* out = (float*)d_out;

  char* ws = (char*)d_ws;
  size_t off = 0;
  auto alloc = [&](size_t bytes) {
    void* p = ws + off;
    off = (off + bytes + 255) & ~(size_t)255;
    return p;
  };
  const int R = B_ * N_;  // 16384
  float4* edge    = (float4*)alloc((size_t)R * CAP * 16);
  int*    cnt     = (int*)   alloc((size_t)R * 4);
  float*  deginv  = (float*) alloc((size_t)R * 4);
  float*  wpack   = (float*) alloc((size_t)128 * NCOL * 4);
  float*  hw      = (float*) alloc((size_t)R * NCOL * 4);
  float*  hb1     = (float*) alloc((size_t)R * F_ * 4);
  float*  hb2     = (float*) alloc((size_t)R * F_ * 4);
  unsigned int* gmax = (unsigned int*)alloc((size_t)B_ * F_ * 4);

  preprocess_kernel<<<R, 512, 0, stream>>>(adj, coord, edge, cnt, deginv);
  zerog_kernel<<<(B_ * F_ + 255) / 256, 256, 0, stream>>>(gmax);

  // layer 0 (Cin=128)
  packw_kernel<<<(128 * NCOL + 255) / 256, 256, 0, stream>>>(w0, root0, 128, wpack);
  gemm_kernel<<<dim3(R / 128, NCOL / 128), 256, 0, stream>>>(x, wpack, hw, 128);
  aggregate_kernel<<<R / 4, 256, 0, stream>>>(hw, edge, cnt, deginv, b0, hb1, nullptr);

  // layer 1 (Cin=64)
  packw_kernel<<<(64 * NCOL + 255) / 256, 256, 0, stream>>>(w1, root1, 64, wpack);
  gemm_kernel<<<dim3(R / 128, NCOL / 128), 256, 0, stream>>>(hb1, wpack, hw, 64);
  aggregate_kernel<<<R / 4, 256, 0, stream>>>(hw, edge, cnt, deginv, b1, hb2, nullptr);

  // layer 2 (Cin=64) — fused max-pool
  packw_kernel<<<(64 * NCOL + 255) / 256, 256, 0, stream>>>(w2, root2, 64, wpack);
  gemm_kernel<<<dim3(R / 128, NCOL / 128), 256, 0, stream>>>(hb2, wpack, hw, 64);
  aggregate_kernel<<<R / 4, 256, 0, stream>>>(hw, edge, cnt, deginv, b2, hb1, gmax);

  fc_kernel<<<B_, 64, 0, stream>>>((const float*)gmax, fcw, fcb, out);
}

// Round 5
// 277.636 us; speedup vs baseline: 1.7776x; 1.1377x over previous
//
#include <hip/hip_runtime.h>

// SplineCNN on MI355X.
// Sparse edge extraction (adj ~6% dense, basis shared across layers);
// per-layer: split-bf16 MFMA GEMM [B*N,3K]x[3K,640] -> sparse aggregate
// (+root+bias+relu, emits next layer's split-bf16 input).
// Split-bf16: v = hi + lo (bf16 each); A slabs [hi|lo|hi], W slabs [hi;hi;lo]
// -> C = Ahi*Whi + Alo*Whi + Ahi*Wlo (drop lo*lo, ~5e-4 abs err).
// Aggregate: XCD-swizzled grid (L2 locality), LDS-staged edge lists, x4 unroll.
// Layer-2 aggregate fuses global max-pool via uint-bitcast atomicMax (relu >= 0).

#define B_   32
#define N_   512
#define F_   64
#define CAP  128          // max neighbors per node (mean ~31, 128 is >>6 sigma)
#define NCOL 640          // 9*F (spline kernels) + F (root)

typedef short bf16x8 __attribute__((ext_vector_type(8)));
typedef float f32x4  __attribute__((ext_vector_type(4)));

__device__ __forceinline__ unsigned short to_bf16_rne(float v) {
  unsigned u = __float_as_uint(v);
  unsigned r = u + 0x7fffu + ((u >> 16) & 1u);
  return (unsigned short)(r >> 16);
}
__device__ __forceinline__ float bf16_to_f(unsigned short h) {
  return __uint_as_float(((unsigned)h) << 16);
}

// ---------------- preprocess: edge lists + factored spline basis ----------------
// edge record: float4 { bitcast(m | k0<<16), fx, fy, 1.0 } (w=1 marks valid; zero
// records give all-zero tap weights)
__global__ __launch_bounds__(512) void preprocess_kernel(
    const float* __restrict__ adj, const float* __restrict__ coord,
    float4* __restrict__ edge, int* __restrict__ cnt_out,
    float* __restrict__ deginv_out) {
  int row = blockIdx.x;          // b*N + n
  int b = row >> 9;
  int tid = threadIdx.x;         // == m
  int lane = tid & 63, wave = tid >> 6;
  __shared__ int wcnt[8];
  float a = adj[(size_t)row * N_ + tid];
  bool flag = (a != 0.0f);
  unsigned long long ball = __ballot(flag);
  if (lane == 0) wcnt[wave] = __popcll(ball);
  __syncthreads();
  int woff = 0, total = 0;
  #pragma unroll
  for (int i = 0; i < 8; ++i) { int c = wcnt[i]; if (i < wave) woff += c; total += c; }
  if (flag) {
    int pos = woff + __popcll(ball & ((1ULL << lane) - 1));
    if (pos < CAP) {
      int m = tid;
      float cxn = coord[(size_t)row * 2 + 0];
      float cyn = coord[(size_t)row * 2 + 1];
      float cxm = coord[(size_t)(b * N_ + m) * 2 + 0];
      float cym = coord[(size_t)(b * N_ + m) * 2 + 1];
      float vx = (cxm - cxn + 1.0f) * 0.5f * 2.0f;
      float vy = (cym - cyn + 1.0f) * 0.5f * 2.0f;
      float i0x = fminf(fmaxf(floorf(vx), 0.0f), 1.0f);
      float i0y = fminf(fmaxf(floorf(vy), 0.0f), 1.0f);
      float fx = vx - i0x, fy = vy - i0y;
      int k0c = (int)i0x * 3 + (int)i0y;
      edge[(size_t)row * CAP + pos] =
          make_float4(__int_as_float(m | (k0c << 16)), fx, fy, 1.0f);
    }
  }
  if (tid == 0) {
    cnt_out[row] = total > CAP ? CAP : total;
    deginv_out[row] = 1.0f / (float)(total > 0 ? total : 1);
  }
}

// ---------------- convert x (fp32 [M,128]) -> split-bf16 A [M, 384] ----------------
__global__ void convx_kernel(const float* __restrict__ x, unsigned short* __restrict__ a) {
  int idx = blockIdx.x * blockDim.x + threadIdx.x;
  if (idx >= B_ * N_ * 128) return;
  int row = idx >> 7, k = idx & 127;
  float v = x[idx];
  unsigned short hi = to_bf16_rne(v);
  unsigned short lo = to_bf16_rne(v - bf16_to_f(hi));
  size_t base = (size_t)row * 384;
  a[base + k] = hi;
  a[base + 128 + k] = lo;
  a[base + 256 + k] = hi;
}

// ---- pack w (9 slices)+root -> W^T split-bf16 [640 n][3*cin k'] (slabs hi,hi,lo) ----
__global__ void packw_kernel(const float* __restrict__ w, const float* __restrict__ root,
                             int cin, unsigned short* __restrict__ wt) {
  int idx = blockIdx.x * blockDim.x + threadIdx.x;
  int total = NCOL * cin;
  if (idx >= total) return;
  int n = idx / cin, k = idx - n * cin;
  int kk = n >> 6, f = n & 63;
  float v = (kk < 9) ? w[((size_t)kk * cin + k) * F_ + f]
                     : root[(size_t)k * F_ + f];
  unsigned short hi = to_bf16_rne(v);
  unsigned short lo = to_bf16_rne(v - bf16_to_f(hi));
  size_t base = (size_t)n * (3 * cin);
  wt[base + k] = hi;
  wt[base + cin + k] = hi;
  wt[base + 2 * cin + k] = lo;
}

// ---------------- split-bf16 MFMA GEMM: C[M,640] = A[M,KP] * Wt[640,KP]^T ----------------
// 128x128 tile, 256 threads = 4 waves (2x2 of 64x64), 16x16x32 bf16 MFMA, BK=64.
// LDS rows padded +8 bf16 (stride 144B = 9 words -> conflict-free b128 frag reads).
#define BK 64
#define LDK (BK + 8)
__global__ __launch_bounds__(256) void gemm_mfma_kernel(
    const unsigned short* __restrict__ A,   // [M][KP]
    const unsigned short* __restrict__ Wt,  // [640][KP]  (W^T, n-major)
    float* __restrict__ C, int KP) {
  __shared__ unsigned short As[128 * LDK];
  __shared__ unsigned short Ws[128 * LDK];
  int bm = blockIdx.x * 128;
  int bn = blockIdx.y * 128;
  int tid = threadIdx.x;
  int wave = tid >> 6, lane = tid & 63;
  int mw = (wave & 1) * 64, nw = (wave >> 1) * 64;
  int lr = lane & 15, quad = lane >> 4;

  f32x4 acc[4][4] = {};
  for (int k0 = 0; k0 < KP; k0 += BK) {
    #pragma unroll
    for (int i = 0; i < 4; ++i) {
      int c = tid + i * 256;            // 0..1023 chunks of 16B
      int row = c >> 3, ck = (c & 7) * 8;
      *(float4*)&As[row * LDK + ck] =
          *(const float4*)&A[(size_t)(bm + row) * KP + k0 + ck];
      *(float4*)&Ws[row * LDK + ck] =
          *(const float4*)&Wt[(size_t)(bn + row) * KP + k0 + ck];
    }
    __syncthreads();
    #pragma unroll
    for (int kk = 0; kk < BK; kk += 32) {
      bf16x8 af[4], bf[4];
      #pragma unroll
      for (int i = 0; i < 4; ++i)
        af[i] = *(const bf16x8*)&As[(mw + 16 * i + lr) * LDK + kk + quad * 8];
      #pragma unroll
      for (int j = 0; j < 4; ++j)
        bf[j] = *(const bf16x8*)&Ws[(nw + 16 * j + lr) * LDK + kk + quad * 8];
      #pragma unroll
      for (int i = 0; i < 4; ++i)
        #pragma unroll
        for (int j = 0; j < 4; ++j)
          acc[i][j] = __builtin_amdgcn_mfma_f32_16x16x32_bf16(af[i], bf[j], acc[i][j], 0, 0, 0);
    }
    __syncthreads();
  }
  // epilogue: C/D layout col=lane&15, row=quad*4+reg (m89-verified)
  #pragma unroll
  for (int i = 0; i < 4; ++i)
    #pragma unroll
    for (int j = 0; j < 4; ++j)
      #pragma unroll
      for (int r = 0; r < 4; ++r) {
        int m = bm + mw + 16 * i + quad * 4 + r;
        int n = bn + nw + 16 * j + lr;
        C[(size_t)m * NCOL + n] = acc[i][j][r];
      }
}

// ---------------- sparse aggregate ----------------
// 256 threads = 4 waves, one row per wave. XCD-swizzled (blockIdx&7 = XCD).
// Edge lists staged to LDS, padded to x4 with zero records; x4 unrolled gathers.
// Emits next layer's split-bf16 A (aout: [row][192] = hi|lo|hi) and/or gmax.
__global__ __launch_bounds__(256) void aggregate_kernel(
    const float* __restrict__ hw,
    const float4* __restrict__ edge,
    const int* __restrict__ cnt, const float* __restrict__ deginv,
    const float* __restrict__ bias,
    unsigned short* __restrict__ aout,
    unsigned int* __restrict__ gmax) {
  __shared__ float4 esh[4][CAP];
  int wave = threadIdx.x >> 6;
  int lane = threadIdx.x & 63;
  int f = lane;
  int xcd = blockIdx.x & 7;
  int j = blockIdx.x >> 3;
  int b = xcd * 4 + (j >> 7);
  int row = b * N_ + ((j & 127) << 2) + wave;
  int c = cnt[row];
  int cpad = (c + 3) & ~3;
  size_t ebase = (size_t)row * CAP;
  for (int i = lane; i < cpad; i += 64)
    esh[wave][i] = (i < c) ? edge[ebase + i] : make_float4(0.f, 0.f, 0.f, 0.f);
  __syncthreads();

  float di = deginv[row];
  const float* hwb = hw + (size_t)b * N_ * NCOL;
  float acc0 = 0.f, acc1 = 0.f, acc2 = 0.f, acc3 = 0.f;
  for (int e0 = 0; e0 < cpad; e0 += 4) {
    int off[4];
    float w00[4], w01[4], w10[4], w11[4];
    #pragma unroll
    for (int q = 0; q < 4; ++q) {
      float4 er = esh[wave][e0 + q];
      int mk = __float_as_int(er.x);
      off[q] = (mk & 0xffff) * NCOL + (mk >> 16) * F_ + f;
      float bx1 = er.y, by1 = er.z, v = er.w;
      float bx0 = v - bx1, by0 = v - by1;
      w00[q] = bx0 * by0; w01[q] = bx0 * by1;
      w10[q] = bx1 * by0; w11[q] = bx1 * by1;
    }
    float t0[4], t1[4], t2[4], t3[4];
    #pragma unroll
    for (int q = 0; q < 4; ++q) {
      const float* p = hwb + off[q];
      t0[q] = p[0]; t1[q] = p[F_]; t2[q] = p[3 * F_]; t3[q] = p[4 * F_];
    }
    acc0 += w00[0] * t0[0] + w01[0] * t1[0] + w10[0] * t2[0] + w11[0] * t3[0];
    acc1 += w00[1] * t0[1] + w01[1] * t1[1] + w10[1] * t2[1] + w11[1] * t3[1];
    acc2 += w00[2] * t0[2] + w01[2] * t1[2] + w10[2] * t2[2] + w11[2] * t3[2];
    acc3 += w00[3] * t0[3] + w01[3] * t1[3] + w10[3] * t2[3] + w11[3] * t3[3];
  }
  float rootv = hw[(size_t)row * NCOL + 9 * F_ + f];
  float val = fmaxf(((acc0 + acc1) + (acc2 + acc3)) * di + rootv + bias[f], 0.0f);
  if (aout) {
    unsigned short hi = to_bf16_rne(val);
    unsigned short lo = to_bf16_rne(val - bf16_to_f(hi));
    size_t base = (size_t)row * 192;
    aout[base + f] = hi;
    aout[base + 64 + f] = lo;
    aout[base + 128 + f] = hi;
  }
  if (gmax) {
    // relu output >= 0 -> IEEE bits monotone under unsigned compare
    atomicMax(&gmax[b * F_ + f], __float_as_uint(val));
  }
}

// ---------------- zero the pooled-max buffer ----------------
__global__ void zerog_kernel(unsigned int* __restrict__ g) {
  int i = blockIdx.x * blockDim.x + threadIdx.x;
  if (i < B_ * F_) g[i] = 0u;
}

// ---------------- FC from pooled features ----------------
__global__ __launch_bounds__(64) void fc_kernel(
    const float* __restrict__ g, const float* __restrict__ fcw,
    const float* __restrict__ fcb, float* __restrict__ out) {
  int b = blockIdx.x;
  int f = threadIdx.x;
  __shared__ float gs[64];
  gs[f] = g[b * F_ + f];
  __syncthreads();
  if (f < 10) {
    float s = fcb[f];
    #pragma unroll
    for (int c = 0; c < 64; ++c) s += gs[c] * fcw[c * 10 + f];
    out[b * 10 + f] = s;
  }
}

extern "C" void kernel_launch(void* const* d_in, const int* in_sizes, int n_in,
                              void* d_out, int out_size, void* d_ws, size_t ws_size,
                              hipStream_t stream) {
  const float* x     = (const float*)d_in[0];
  const float* coord = (const float*)d_in[1];
  const float* adj   = (const float*)d_in[2];
  const float* w0    = (const float*)d_in[3];
  const float* root0 = (const float*)d_in[4];
  const float* b0    = (const float*)d_in[5];
  const float* w1    = (const float*)d_in[6];
  const float* root1 = (const float*)d_in[7];
  const float* b1    = (const float*)d_in[8];
  const float* w2    = (const float*)d_in[9];
  const float* root2 = (const float*)d_in[10];
  const float* b2    = (const float*)d_in[11];
  const float* fcw   = (const float*)d_in[12];
  const float* fcb   = (const float*)d_in[13];
  float* out = (float*)d_out;

  char* ws = (char*)d_ws;
  size_t off = 0;
  auto alloc = [&](size_t bytes) {
    void* p = ws + off;
    off = (off + bytes + 255) & ~(size_t)255;
    return p;
  };
  const int R = B_ * N_;  // 16384
  float4* edge    = (float4*)alloc((size_t)R * CAP * 16);
  int*    cnt     = (int*)   alloc((size_t)R * 4);
  float*  deginv  = (float*) alloc((size_t)R * 4);
  unsigned short* abf0 = (unsigned short*)alloc((size_t)R * 384 * 2);
  unsigned short* abfN = (unsigned short*)alloc((size_t)R * 192 * 2);
  unsigned short* wt   = (unsigned short*)alloc((size_t)NCOL * 384 * 2);
  float*  hw      = (float*) alloc((size_t)R * NCOL * 4);
  unsigned int* gmax = (unsigned int*)alloc((size_t)B_ * F_ * 4);

  preprocess_kernel<<<R, 512, 0, stream>>>(adj, coord, edge, cnt, deginv);
  zerog_kernel<<<(B_ * F_ + 255) / 256, 256, 0, stream>>>(gmax);
  convx_kernel<<<(R * 128 + 255) / 256, 256, 0, stream>>>(x, abf0);

  // layer 0 (Cin=128, KP=384)
  packw_kernel<<<(NCOL * 128 + 255) / 256, 256, 0, stream>>>(w0, root0, 128, wt);
  gemm_mfma_kernel<<<dim3(R / 128, NCOL / 128), 256, 0, stream>>>(abf0, wt, hw, 384);
  aggregate_kernel<<<R / 4, 256, 0, stream>>>(hw, edge, cnt, deginv, b0, abfN, nullptr);

  // layer 1 (Cin=64, KP=192)
  packw_kernel<<<(NCOL * 64 + 255) / 256, 256, 0, stream>>>(w1, root1, 64, wt);
  gemm_mfma_kernel<<<dim3(R / 128, NCOL / 128), 256, 0, stream>>>(abfN, wt, hw, 192);
  aggregate_kernel<<<R / 4, 256, 0, stream>>>(hw, edge, cnt, deginv, b1, abfN, nullptr);

  // layer 2 (Cin=64, KP=192) — fused max-pool
  packw_kernel<<<(NCOL * 64 + 255) / 256, 256, 0, stream>>>(w2, root2, 64, wt);
  gemm_mfma_kernel<<<dim3(R / 128, NCOL / 128), 256, 0, stream>>>(abfN, wt, hw, 192);
  aggregate_kernel<<<R / 4, 256, 0, stream>>>(hw, edge, cnt, deginv, b2, nullptr, gmax);

  fc_kernel<<<B_, 64, 0, stream>>>((const float*)gmax, fcw, fcb, out);
}